// Round 11
// baseline (186.685 us; speedup 1.0000x reference)
//
#include <hip/hip_runtime.h>
#include <math.h>

#define BB 16
#define LL 4096
#define CC 64
#define HD 128

typedef __attribute__((ext_vector_type(8))) short short8;
typedef __attribute__((ext_vector_type(8))) unsigned short ushort8;
typedef __attribute__((ext_vector_type(4))) float floatx4;

__constant__ float c_lo[8] = {
    -0.010597401784997278f, 0.032883011666982945f, 0.030841381835986965f,
    -0.18703481171888114f, -0.02798376941698385f, 0.6308807679295904f,
    0.7148465705525415f, 0.23037781330885523f};
__constant__ float c_hi[8] = {
    -0.23037781330885523f, 0.7148465705525415f, -0.6308807679295904f,
    -0.02798376941698385f, 0.18703481171888114f, 0.030841381835986965f,
    -0.032883011666982945f, -0.010597401784997278f};

// tanh-GELU in sigmoid form, max abs err vs erf-GELU ~3e-4
__device__ __forceinline__ float gelu_fast(float x) {
    float u = x * fmaf(0.044715f * x, x, 1.0f) * 1.5957691216057308f;
    return x / (1.0f + __expf(-u));
}
__device__ __forceinline__ unsigned short f2b(float f) {   // f32 -> bf16 RNE
    unsigned int u = __float_as_uint(f);
    u = u + 0x7FFFu + ((u >> 16) & 1u);
    return (unsigned short)(u >> 16);
}
__device__ __forceinline__ float b2f(unsigned short s) {
    return __uint_as_float(((unsigned int)s) << 16);
}

// ---------------- zproj (+ fused tail blocks: Bmix pack / FiLM / denom+cnt) ----------------
// Operand-swapped MFMA: D[l][h] -> 8x ushort4 stores.

__global__ __launch_bounds__(256) void zproj_kernel(
    const float* __restrict__ x, const float* __restrict__ mask,
    const float* __restrict__ W_in, const float* __restrict__ b_in,
    unsigned short* __restrict__ z_bf,
    const float* __restrict__ W_mix, unsigned short* __restrict__ Bmix,
    const float* __restrict__ flow, const float* __restrict__ Wgb,
    const float* __restrict__ bgb, const float* __restrict__ Wg,
    const float* __restrict__ bg, float* __restrict__ film_ws,
    float* __restrict__ gate_ws, float* __restrict__ denom_ws,
    unsigned int* __restrict__ cnt) {
    __shared__ float red[256];
    int blk = blockIdx.x;
    int tid = threadIdx.x;

    if (blk >= BB * 64) {
        int e = blk - BB * 64;
        if (e < 64) {                               // Bmix pack: idx = ((h>>3)*128+g)*8+(h&7)
            int q = e * 256 + tid;                  // 16384
            int g = (q >> 3) & 127;
            int h = ((q >> 10) << 3) | (q & 7);
            Bmix[q] = f2b(W_mix[g * HD + h]);
        } else if (e < 128) {                       // FiLM
            int bf = e - 64;                        // b*4 + f
            int f = bf & 3;
            int b = bf >> 2;
            const float* fl = flow + b * 24;
            const float* wrow = Wgb + ((size_t)(f * 256 + tid)) * 24;
            float acc = bgb[f * 256 + tid];
#pragma unroll
            for (int j = 0; j < 24; ++j) acc = fmaf(wrow[j], fl[j], acc);
            film_ws[(size_t)bf * 256 + tid] = acc;
            if (tid == 0) {
                float g = bg[f];
#pragma unroll
                for (int j = 0; j < 24; ++j) g = fmaf(Wg[f * 24 + j], fl[j], g);
                gate_ws[bf] = 1.0f / (1.0f + expf(-g));
            }
        } else {                                    // denom + counter zero
            int b = e - 128;
            float s = 0.f;
            const float4* mp = (const float4*)(mask + (size_t)b * LL);
            for (int i = tid; i < LL / 4; i += 256) {
                float4 m = mp[i];
                s += m.x + m.y + m.z + m.w;
            }
            red[tid] = s; __syncthreads();
            for (int st = 128; st > 0; st >>= 1) {
                if (tid < st) red[tid] += red[tid + st];
                __syncthreads();
            }
            if (tid == 0) {
                denom_ws[b] = fmaxf(red[0], 1.0f);
                cnt[b] = 0u;
            }
        }
        return;
    }

    int b = blk >> 6;
    int l0 = (blk & 63) << 6;
    int lane = tid & 63;
    int w = tid >> 6;
    int h_half = w >> 1;
    int l_q = w & 1;
    int ln15 = lane & 15, lq4 = lane >> 4;

    int lr0 = l0 + l_q * 32 + ln15;
    int lr1 = lr0 + 16;
    float mk0 = mask[(size_t)b * LL + lr0];
    float mk1 = mask[(size_t)b * LL + lr1];

    floatx4 acc[4][2];
#pragma unroll
    for (int i = 0; i < 4; ++i)
#pragma unroll
        for (int j = 0; j < 2; ++j) acc[i][j] = (floatx4){0.f, 0.f, 0.f, 0.f};

#pragma unroll
    for (int ks = 0; ks < 2; ++ks) {
        int c0 = ks * 32 + (lq4 << 3);
        short8 bf0, bf1;
        {
            const float* xp = x + ((size_t)b * LL + lr0) * CC + c0;
            float4 xa = *(const float4*)xp;
            float4 xb = *(const float4*)(xp + 4);
            bf0[0] = (short)f2b(xa.x * mk0); bf0[1] = (short)f2b(xa.y * mk0);
            bf0[2] = (short)f2b(xa.z * mk0); bf0[3] = (short)f2b(xa.w * mk0);
            bf0[4] = (short)f2b(xb.x * mk0); bf0[5] = (short)f2b(xb.y * mk0);
            bf0[6] = (short)f2b(xb.z * mk0); bf0[7] = (short)f2b(xb.w * mk0);
        }
        {
            const float* xp = x + ((size_t)b * LL + lr1) * CC + c0;
            float4 xa = *(const float4*)xp;
            float4 xb = *(const float4*)(xp + 4);
            bf1[0] = (short)f2b(xa.x * mk1); bf1[1] = (short)f2b(xa.y * mk1);
            bf1[2] = (short)f2b(xa.z * mk1); bf1[3] = (short)f2b(xa.w * mk1);
            bf1[4] = (short)f2b(xb.x * mk1); bf1[5] = (short)f2b(xb.y * mk1);
            bf1[6] = (short)f2b(xb.z * mk1); bf1[7] = (short)f2b(xb.w * mk1);
        }
        const float* wb = W_in + (size_t)(h_half * 64 + ln15) * CC + c0;
#pragma unroll
        for (int ht = 0; ht < 4; ++ht) {
            const float* wr = wb + (size_t)ht * 16 * CC;
            float4 wa = *(const float4*)wr;
            float4 wc = *(const float4*)(wr + 4);
            short8 af;
            af[0] = (short)f2b(wa.x); af[1] = (short)f2b(wa.y);
            af[2] = (short)f2b(wa.z); af[3] = (short)f2b(wa.w);
            af[4] = (short)f2b(wc.x); af[5] = (short)f2b(wc.y);
            af[6] = (short)f2b(wc.z); af[7] = (short)f2b(wc.w);
            acc[ht][0] = __builtin_amdgcn_mfma_f32_16x16x32_bf16(bf0, af, acc[ht][0], 0, 0, 0);
            acc[ht][1] = __builtin_amdgcn_mfma_f32_16x16x32_bf16(bf1, af, acc[ht][1], 0, 0, 0);
        }
    }

#pragma unroll
    for (int ht = 0; ht < 4; ++ht) {
        int h = h_half * 64 + ht * 16 + ln15;        // fixed per lane
        float bi = b_in[h];
        unsigned short* zr = z_bf + ((size_t)(b * HD + h)) * LL;
#pragma unroll
        for (int j = 0; j < 2; ++j) {
            int lbase = l0 + l_q * 32 + j * 16 + (lq4 << 2);
            ushort4 o;
            o.x = f2b(acc[ht][j][0] + bi);
            o.y = f2b(acc[ht][j][1] + bi);
            o.z = f2b(acc[ht][j][2] + bi);
            o.w = f2b(acc[ht][j][3] + bi);
            *(ushort4*)(zr + lbase) = o;
        }
    }
}

// ---------------- wavelet helpers ----------------

__device__ __forceinline__ void analysis_step(const float* __restrict__ src,
                                              float* __restrict__ lo_dst,
                                              float* __restrict__ hi_dst,
                                              int half, int tid) {
    int len = half << 1;
    for (int q = tid; q < (half >> 2); q += 256) {
        int n0 = q << 2;
        float lo[4], hi[4];
        if (n0 + 4 == half) {                       // only quad that wraps
#pragma unroll
            for (int i = 0; i < 4; ++i) {
                float l = 0.f, hh = 0.f;
#pragma unroll
                for (int k = 0; k < 8; ++k) {
                    float v = src[(2 * (n0 + i) + k) & (len - 1)];
                    l = fmaf(c_lo[k], v, l);
                    hh = fmaf(c_hi[k], v, hh);
                }
                lo[i] = l; hi[i] = hh;
            }
        } else {
            float sv[16];
            const float* sp = src + (n0 << 1);
            *(float4*)&sv[0]  = *(const float4*)(sp);
            *(float4*)&sv[4]  = *(const float4*)(sp + 4);
            *(float4*)&sv[8]  = *(const float4*)(sp + 8);
            *(float4*)&sv[12] = *(const float4*)(sp + 12);
#pragma unroll
            for (int i = 0; i < 4; ++i) {
                float l = 0.f, hh = 0.f;
#pragma unroll
                for (int k = 0; k < 8; ++k) {
                    l = fmaf(c_lo[k], sv[2 * i + k], l);
                    hh = fmaf(c_hi[k], sv[2 * i + k], hh);
                }
                lo[i] = l; hi[i] = hh;
            }
        }
        *(float4*)&lo_dst[n0] = make_float4(lo[0], lo[1], lo[2], lo[3]);
        *(float4*)&hi_dst[n0] = make_float4(hi[0], hi[1], hi[2], hi[3]);
    }
}

__device__ __forceinline__ void synth_oct(const float* __restrict__ A,
                                          const float* __restrict__ D,
                                          int m0, int half, float* ov) {
    if (m0 == 0) {                                  // only oct that wraps (backward)
        int mask2 = (half << 1) - 1;
#pragma unroll
        for (int t = 0; t < 8; ++t) {
            int par = t & 1;
            float s = 0.f;
#pragma unroll
            for (int j = 0; j < 4; ++j) {
                int k = 2 * j + par;
                int idx = ((t - k) & mask2) >> 1;
                s = fmaf(c_lo[k], A[idx], s);
                s = fmaf(c_hi[k], D[idx], s);
            }
            ov[t] = s;
        }
    } else {
        float av[8], dv[8];
        *(float4*)&av[0] = *(const float4*)(A + m0 - 4);
        *(float4*)&av[4] = *(const float4*)(A + m0);
        *(float4*)&dv[0] = *(const float4*)(D + m0 - 4);
        *(float4*)&dv[4] = *(const float4*)(D + m0);
#pragma unroll
        for (int t = 0; t < 4; ++t) {
            float e = 0.f, o = 0.f;
#pragma unroll
            for (int j = 0; j < 4; ++j) {
                float xa = av[t + 4 - j], xd = dv[t + 4 - j];
                e = fmaf(c_lo[2 * j], xa, e);     e = fmaf(c_hi[2 * j], xd, e);
                o = fmaf(c_lo[2 * j + 1], xa, o); o = fmaf(c_hi[2 * j + 1], xd, o);
            }
            ov[2 * t] = e;
            ov[2 * t + 1] = o;
        }
    }
}

__device__ __forceinline__ void synth_step(const float* __restrict__ A,
                                           const float* __restrict__ D,
                                           float* __restrict__ dst,
                                           int half, int tid) {
    for (int q = tid; q < (half >> 2); q += 256) {
        int m0 = q << 2;
        int i0 = m0 << 1;
        float ov[8];
        synth_oct(A, D, m0, half, ov);
        *(float4*)&dst[i0]     = make_float4(ov[0], ov[1], ov[2], ov[3]);
        *(float4*)&dst[i0 + 4] = make_float4(ov[4], ov[5], ov[6], ov[7]);
    }
}

// ---------------- per-row wavelet: 24 KB LDS, direct-global z reads ----------------

__global__ __launch_bounds__(256) void wavelet_kernel(const unsigned short* __restrict__ z_bf,
                                                      unsigned short* __restrict__ s_bf,
                                                      const float* __restrict__ film_ws,
                                                      const float* __restrict__ gate_ws,
                                                      const float* __restrict__ lam_raw,
                                                      float* __restrict__ lam_ws) {
    __shared__ float d1[2048];
    __shared__ float d2[1024];
    __shared__ float Aq[2048];
    __shared__ float Bq[1024];

    int blk = blockIdx.x;
    int b = blk >> 7;
    int h = blk & 127;
    int tid = threadIdx.x;
    const unsigned short* zg = z_bf + ((size_t)(b * HD + h)) * LL;
    unsigned short* sg = s_bf + ((size_t)(b * HD + h)) * LL;

    for (int q = tid; q < 512; q += 256) {
        int n0 = q << 2;
        float sv[16];
        if (n0 == 2044) {                           // the wrapping quad
#pragma unroll
            for (int j = 0; j < 14; ++j)
                sv[j] = b2f(zg[(2 * n0 + j) & 4095]);
            sv[14] = 0.f; sv[15] = 0.f;
        } else {
            ushort8 va = *(const ushort8*)(zg + (n0 << 1));
            ushort8 vb = *(const ushort8*)(zg + (n0 << 1) + 8);
#pragma unroll
            for (int j = 0; j < 8; ++j) {
                sv[j]     = b2f(va[j]);
                sv[8 + j] = b2f(vb[j]);
            }
        }
        float lo[4], hi[4];
#pragma unroll
        for (int i = 0; i < 4; ++i) {
            float l = 0.f, hh = 0.f;
#pragma unroll
            for (int k = 0; k < 8; ++k) {
                l = fmaf(c_lo[k], sv[2 * i + k], l);
                hh = fmaf(c_hi[k], sv[2 * i + k], hh);
            }
            lo[i] = l; hi[i] = hh;
        }
        *(float4*)&Aq[n0] = make_float4(lo[0], lo[1], lo[2], lo[3]);
        *(float4*)&d1[n0] = make_float4(hi[0], hi[1], hi[2], hi[3]);
    }
    __syncthreads();
    analysis_step(Aq, Bq, d2, 1024, tid);        // L2
    __syncthreads();
    analysis_step(Bq, Aq, Aq + 512, 512, tid);   // L3
    __syncthreads();

    float sc0, sh0, sc1, sh1, sc2, sh2, sc3, sh3;
    {
        int base = b * 4;
#define FILM_COEF(bd, SC, SH)                                              \
        {   float ga = film_ws[((size_t)(base + bd)) * 256 + h];           \
            float be = film_ws[((size_t)(base + bd)) * 256 + 128 + h];     \
            float gt = gate_ws[base + bd];                                 \
            SC = 1.0f + gt * ga; SH = gt * be; }
        FILM_COEF(0, sc0, sh0) FILM_COEF(1, sc1, sh1)
        FILM_COEF(2, sc2, sh2) FILM_COEF(3, sc3, sh3)
#undef FILM_COEF
    }

    float* p0 = &Aq[tid << 2];
    float* p1 = &d1[tid << 2];
    float* p2 = &d1[1024 + (tid << 2)];
    float* p3 = &d2[tid << 2];
    bool lowhalf = (tid < 128);
    float scA = lowhalf ? sc0 : sc3, shA = lowhalf ? sh0 : sh3;

    float4 f0 = *(float4*)p0, f1 = *(float4*)p1, f2v = *(float4*)p2, f3 = *(float4*)p3;
#define FILMV(V, SC, SH)                                                   \
    { V.x = fmaf(V.x, SC, SH); V.y = fmaf(V.y, SC, SH);                    \
      V.z = fmaf(V.z, SC, SH); V.w = fmaf(V.w, SC, SH); }
    FILMV(f0, scA, shA) FILMV(f1, sc1, sh1) FILMV(f2v, sc1, sh1) FILMV(f3, sc2, sh2)
#undef FILMV
    float sA = fabsf(f0.x) + fabsf(f0.y) + fabsf(f0.z) + fabsf(f0.w);
    float s1 = fabsf(f1.x) + fabsf(f1.y) + fabsf(f1.z) + fabsf(f1.w)
             + fabsf(f2v.x) + fabsf(f2v.y) + fabsf(f2v.z) + fabsf(f2v.w);
    float s2 = fabsf(f3.x) + fabsf(f3.y) + fabsf(f3.z) + fabsf(f3.w);
#pragma unroll
    for (int off = 32; off > 0; off >>= 1) {
        sA += __shfl_xor(sA, off);
        s1 += __shfl_xor(s1, off);
        s2 += __shfl_xor(s2, off);
    }
    if ((tid & 63) == 0)
        ((float4*)Bq)[tid >> 6] = make_float4(lowhalf ? sA : 0.f, s1, s2,
                                              lowhalf ? 0.f : sA);
    __syncthreads();
    float4 r0 = ((const float4*)Bq)[0];
    float4 r1 = ((const float4*)Bq)[1];
    float4 r2 = ((const float4*)Bq)[2];
    float4 r3 = ((const float4*)Bq)[3];
    float lam0 = log1pf(expf(lam_raw[0])) * ((r0.x + r1.x + r2.x + r3.x) * (1.0f / 512.f));
    float lam1 = log1pf(expf(lam_raw[1])) * ((r0.y + r1.y + r2.y + r3.y) * (1.0f / 2048.f));
    float lam2 = log1pf(expf(lam_raw[2])) * ((r0.z + r1.z + r2.z + r3.z) * (1.0f / 1024.f));
    float lam3 = log1pf(expf(lam_raw[3])) * ((r0.w + r1.w + r2.w + r3.w) * (1.0f / 512.f));
    if (tid < 4) {
        float lam = (tid == 0) ? lam0 : (tid == 1) ? lam1 : (tid == 2) ? lam2 : lam3;
        lam_ws[((size_t)(b * 4 + tid)) * 128 + h] = lam;
    }
    float lamA = lowhalf ? lam0 : lam3;
#define THRV(V, LAM)                                                       \
    { float a;                                                             \
      a = fabsf(V.x) - (LAM); V.x = (a > 0.f) ? copysignf(a, V.x) : 0.f;   \
      a = fabsf(V.y) - (LAM); V.y = (a > 0.f) ? copysignf(a, V.y) : 0.f;   \
      a = fabsf(V.z) - (LAM); V.z = (a > 0.f) ? copysignf(a, V.z) : 0.f;   \
      a = fabsf(V.w) - (LAM); V.w = (a > 0.f) ? copysignf(a, V.w) : 0.f; }
    THRV(f0, lamA) THRV(f1, lam1) THRV(f2v, lam1) THRV(f3, lam2)
#undef THRV
    *(float4*)p0 = f0; *(float4*)p1 = f1; *(float4*)p2 = f2v; *(float4*)p3 = f3;
    __syncthreads();

    synth_step(Aq, Aq + 512, Bq, 512, tid);      // R1 -> Bq[0:1024]
    __syncthreads();
    synth_step(Bq, d2, Aq, 1024, tid);           // R2 -> Aq[0:2048]
    __syncthreads();
    for (int q = tid; q < 512; q += 256) {       // R3 + residual + store
        int m0 = q << 2;
        int i0 = m0 << 1;
        float ov[8];
        synth_oct(Aq, d1, m0, 2048, ov);
        ushort8 zin = *(const ushort8*)(zg + i0);
        ushort8 o8;
#pragma unroll
        for (int t = 0; t < 8; ++t) o8[t] = f2b(ov[t] + b2f(zin[t]));
        *(ushort8*)(sg + i0) = o8;
    }
}

// ---------------- mix: MFMA GEMM + fused last-block-per-batch finalize ----------------

union U32x4S8 { unsigned int u[4]; short8 s; };

__global__ __launch_bounds__(256) void mix_kernel(const unsigned short* __restrict__ s_bf,
                                                  const unsigned short* __restrict__ Bmix,
                                                  const float* __restrict__ b_mix,
                                                  const float* __restrict__ mask,
                                                  float* __restrict__ dout,
                                                  float* __restrict__ pool_part,
                                                  const float* __restrict__ lam_ws,
                                                  const float* __restrict__ denom_ws,
                                                  unsigned int* __restrict__ cnt) {
    __shared__ unsigned int T[HD * 32];   // 16 KB, [h][lp ^ (h&31)]; reused as reduce scratch
    __shared__ float pbuf[2][HD];
    __shared__ int lastFlag;

    int blk = blockIdx.x;
    int b = blk >> 6;
    int lt64 = blk & 63;
    int l0 = lt64 << 6;
    int tid = threadIdx.x;
    int lane = tid & 63;
    int w = tid >> 6;
    int l_half = w >> 1, g_half = w & 1;
    int ln15 = lane & 15, lq4 = lane >> 4;

    {
        const unsigned int* src = (const unsigned int*)s_bf;
#pragma unroll
        for (int r = 0; r < 4; ++r) {
            int q = (r << 8) + tid;              // 0..1023
            int hh = q >> 3;                     // 0..127
            int k = q & 7;                       // 16B chunk
            uint4 v = *(const uint4*)(src + (size_t)(b * HD + hh) * (LL / 2) +
                                      (l0 >> 1) + (k << 2));
            int sw = hh & 31;
            unsigned int* tp = T + hh * 32;
            tp[((k << 2) + 0) ^ sw] = v.x;
            tp[((k << 2) + 1) ^ sw] = v.y;
            tp[((k << 2) + 2) ^ sw] = v.z;
            tp[((k << 2) + 3) ^ sw] = v.w;
        }
    }
    __syncthreads();

    floatx4 acc[2][4];
#pragma unroll
    for (int i = 0; i < 2; ++i)
#pragma unroll
        for (int j = 0; j < 4; ++j) acc[i][j] = (floatx4){0.f, 0.f, 0.f, 0.f};

    const unsigned short* Bb = Bmix + (g_half * 64 + ln15) * 8;

#pragma unroll 2
    for (int ks = 0; ks < 4; ++ks) {
        int koct = ks * 4 + lq4;
        short8 a[2], bb[4];
#pragma unroll
        for (int lt = 0; lt < 2; ++lt) {
            int l_loc = l_half * 32 + lt * 16 + ln15;
            int lp = l_loc >> 1;
            int odd = l_loc & 1;
            U32x4S8 cv;
#pragma unroll
            for (int qq = 0; qq < 4; ++qq) {
                int h0 = koct * 8 + 2 * qq;
                unsigned int w0 = T[h0 * 32 + (lp ^ (h0 & 31))];
                unsigned int w1 = T[(h0 + 1) * 32 + (lp ^ ((h0 + 1) & 31))];
                unsigned int e0 = odd ? (w0 >> 16) : (w0 & 0xffffu);
                unsigned int e1 = odd ? (w1 >> 16) : (w1 & 0xffffu);
                cv.u[qq] = e0 | (e1 << 16);
            }
            a[lt] = cv.s;
        }
#pragma unroll
        for (int gt = 0; gt < 4; ++gt)
            bb[gt] = *(const short8*)(Bb + (size_t)koct * 1024 + gt * 128);
        // swapped operands: D[g][l]
#pragma unroll
        for (int lt = 0; lt < 2; ++lt)
#pragma unroll
            for (int gt = 0; gt < 4; ++gt)
                acc[lt][gt] = __builtin_amdgcn_mfma_f32_16x16x32_bf16(bb[gt], a[lt], acc[lt][gt], 0, 0, 0);
    }

    // epilogue: lane = fixed l (ln15), regs = 4 consecutive g
    float4 pacc4[4];
#pragma unroll
    for (int gt = 0; gt < 4; ++gt) pacc4[gt] = make_float4(0.f, 0.f, 0.f, 0.f);

#pragma unroll
    for (int lt = 0; lt < 2; ++lt) {
        int l = l0 + l_half * 32 + lt * 16 + ln15;
        float mkv = mask[(size_t)b * LL + l];
        float* orow = dout + ((size_t)b * LL + l) * HD;
#pragma unroll
        for (int gt = 0; gt < 4; ++gt) {
            int g0q = g_half * 64 + gt * 16 + (lq4 << 2);
            float4 bm = *(const float4*)&b_mix[g0q];
            floatx4 v;
            v[0] = gelu_fast(acc[lt][gt][0] + bm.x) * mkv;
            v[1] = gelu_fast(acc[lt][gt][1] + bm.y) * mkv;
            v[2] = gelu_fast(acc[lt][gt][2] + bm.z) * mkv;
            v[3] = gelu_fast(acc[lt][gt][3] + bm.w) * mkv;
            __builtin_nontemporal_store(v, (floatx4*)&orow[g0q]);
            pacc4[gt].x = fmaf(v[0], mkv, pacc4[gt].x);
            pacc4[gt].y = fmaf(v[1], mkv, pacc4[gt].y);
            pacc4[gt].z = fmaf(v[2], mkv, pacc4[gt].z);
            pacc4[gt].w = fmaf(v[3], mkv, pacc4[gt].w);
        }
    }
#pragma unroll
    for (int gt = 0; gt < 4; ++gt) {
#pragma unroll
        for (int off = 1; off <= 8; off <<= 1) {
            pacc4[gt].x += __shfl_xor(pacc4[gt].x, off);
            pacc4[gt].y += __shfl_xor(pacc4[gt].y, off);
            pacc4[gt].z += __shfl_xor(pacc4[gt].z, off);
            pacc4[gt].w += __shfl_xor(pacc4[gt].w, off);
        }
    }
    if (ln15 == 0) {
#pragma unroll
        for (int gt = 0; gt < 4; ++gt)
            *(float4*)&pbuf[l_half][g_half * 64 + gt * 16 + (lq4 << 2)] = pacc4[gt];
    }
    __syncthreads();
    if (tid < HD)
        pool_part[((size_t)(b * 64 + lt64)) * HD + tid] = pbuf[0][tid] + pbuf[1][tid];

    // ---- last block of this batch performs the finalize (overlapped with other batches)
    __threadfence();
    if (tid == 0) {
        unsigned int old = atomicAdd(&cnt[b], 1u);
        lastFlag = (old == 63u);
    }
    __syncthreads();
    if (!lastFlag) return;
    __threadfence();

    const size_t OUT1 = (size_t)BB * LL * HD;
    const size_t OUT2 = OUT1 + (size_t)BB * HD;
    const size_t OUT3 = OUT2 + BB;
    float* red = (float*)T;            // reuse LDS
    float* rmx = red + 256;
    float denom = denom_ws[b];

    {
        int hh = tid & 127, half2 = tid >> 7;
        float s = 0.f;
        for (int blk2 = half2 * 32; blk2 < half2 * 32 + 32; ++blk2)
            s += pool_part[((size_t)(b * 64 + blk2)) * HD + hh];
        red[tid] = s;
        __syncthreads();
        if (tid < 128)
            dout[OUT1 + (size_t)b * HD + tid] = (red[tid] + red[tid + 128]) / denom;
        __syncthreads();
    }

    float v0 = lam_ws[(size_t)b * 512 + tid];
    float v1 = lam_ws[(size_t)b * 512 + 256 + tid];
    red[tid] = v0 + v1;
    rmx[tid] = fmaxf(v0, v1);
    __syncthreads();
    for (int st = 128; st > 0; st >>= 1) {
        if (tid < st) {
            red[tid] += red[tid + st];
            rmx[tid] = fmaxf(rmx[tid], rmx[tid + st]);
        }
        __syncthreads();
    }
    if (tid == 0) {
        dout[OUT2 + b] = red[0] / 512.0f;
        dout[OUT3 + b] = rmx[0];
    }
}

// ---------------- launch ----------------

extern "C" void kernel_launch(void* const* d_in, const int* in_sizes, int n_in,
                              void* d_out, int out_size, void* d_ws, size_t ws_size,
                              hipStream_t stream) {
    (void)in_sizes; (void)n_in; (void)out_size; (void)ws_size;
    const float* x      = (const float*)d_in[0];
    const float* mask   = (const float*)d_in[1];
    const float* flow   = (const float*)d_in[2];
    const float* W_in   = (const float*)d_in[3];
    const float* b_in   = (const float*)d_in[4];
    const float* W_mix  = (const float*)d_in[5];
    const float* b_mix  = (const float*)d_in[6];
    const float* lam_raw= (const float*)d_in[7];
    const float* Wgb    = (const float*)d_in[8];
    const float* bgb    = (const float*)d_in[9];
    const float* Wg     = (const float*)d_in[10];
    const float* bg     = (const float*)d_in[11];

    unsigned short* z_bf = (unsigned short*)d_ws;                 // 8388608 ushort
    unsigned short* s_bf = z_bf + (size_t)BB * HD * LL;           // 8388608 ushort
    float* film_ws   = (float*)(s_bf + (size_t)BB * HD * LL);     // 16384
    float* gate_ws   = film_ws + BB * 4 * 256;                    // 64
    float* lam_ws    = gate_ws + 64;                              // 8192
    float* pool_part = lam_ws + BB * 4 * 128;                     // 16*64*128 = 131072
    float* denom_ws  = pool_part + (size_t)BB * 64 * HD;          // 16
    unsigned int* cnt = (unsigned int*)(denom_ws + 16);           // 16
    unsigned short* Bmix = (unsigned short*)(cnt + 16);           // 16384 ushort

    float* out = (float*)d_out;

    hipLaunchKernelGGL(zproj_kernel, dim3(BB * 64 + 144), dim3(256), 0, stream,
                       x, mask, W_in, b_in, z_bf,
                       W_mix, Bmix, flow, Wgb, bgb, Wg, bg, film_ws, gate_ws,
                       denom_ws, cnt);
    hipLaunchKernelGGL(wavelet_kernel, dim3(BB * HD), dim3(256), 0, stream,
                       z_bf, s_bf, film_ws, gate_ws, lam_raw, lam_ws);
    hipLaunchKernelGGL(mix_kernel, dim3(BB * (LL / 64)), dim3(256), 0, stream,
                       s_bf, Bmix, b_mix, mask, out, pool_part, lam_ws, denom_ws, cnt);
}

// Round 12
// 66.636 us; speedup vs baseline: 2.8016x; 2.8016x over previous
//
#include <hip/hip_runtime.h>
#include <math.h>

#define BB 16
#define LL 4096
#define CC 64
#define HD 128

typedef __attribute__((ext_vector_type(8))) short short8;
typedef __attribute__((ext_vector_type(8))) unsigned short ushort8;
typedef __attribute__((ext_vector_type(4))) float floatx4;

__constant__ float c_lo[8] = {
    -0.010597401784997278f, 0.032883011666982945f, 0.030841381835986965f,
    -0.18703481171888114f, -0.02798376941698385f, 0.6308807679295904f,
    0.7148465705525415f, 0.23037781330885523f};
__constant__ float c_hi[8] = {
    -0.23037781330885523f, 0.7148465705525415f, -0.6308807679295904f,
    -0.02798376941698385f, 0.18703481171888114f, 0.030841381835986965f,
    -0.032883011666982945f, -0.010597401784997278f};

// tanh-GELU in sigmoid form, max abs err vs erf-GELU ~3e-4
__device__ __forceinline__ float gelu_fast(float x) {
    float u = x * fmaf(0.044715f * x, x, 1.0f) * 1.5957691216057308f;
    return x / (1.0f + __expf(-u));
}
__device__ __forceinline__ unsigned short f2b(float f) {   // f32 -> bf16 RNE
    unsigned int u = __float_as_uint(f);
    u = u + 0x7FFFu + ((u >> 16) & 1u);
    return (unsigned short)(u >> 16);
}
__device__ __forceinline__ float b2f(unsigned short s) {
    return __uint_as_float(((unsigned int)s) << 16);
}

// ---------------- zproj (+ fused pack blocks for Bmix / FiLM) ----------------
// Operand-swapped MFMA: D[l][h] -> 8x ushort4 stores.

__global__ __launch_bounds__(256) void zproj_kernel(
    const float* __restrict__ x, const float* __restrict__ mask,
    const float* __restrict__ W_in, const float* __restrict__ b_in,
    unsigned short* __restrict__ z_bf,
    const float* __restrict__ W_mix, unsigned short* __restrict__ Bmix,
    const float* __restrict__ flow, const float* __restrict__ Wgb,
    const float* __restrict__ bgb, const float* __restrict__ Wg,
    const float* __restrict__ bg, float* __restrict__ film_ws,
    float* __restrict__ gate_ws) {
    int blk = blockIdx.x;
    int tid = threadIdx.x;

    if (blk >= BB * 64) {
        int e = blk - BB * 64;
        if (e < 64) {                               // Bmix pack: idx = ((h>>3)*128+g)*8+(h&7)
            int q = e * 256 + tid;                  // 16384
            int g = (q >> 3) & 127;
            int h = ((q >> 10) << 3) | (q & 7);
            Bmix[q] = f2b(W_mix[g * HD + h]);
        } else {                                    // FiLM
            int bf = e - 64;                        // b*4 + f
            int f = bf & 3;
            int b = bf >> 2;
            const float* fl = flow + b * 24;
            const float* wrow = Wgb + ((size_t)(f * 256 + tid)) * 24;
            float acc = bgb[f * 256 + tid];
#pragma unroll
            for (int j = 0; j < 24; ++j) acc = fmaf(wrow[j], fl[j], acc);
            film_ws[(size_t)bf * 256 + tid] = acc;
            if (tid == 0) {
                float g = bg[f];
#pragma unroll
                for (int j = 0; j < 24; ++j) g = fmaf(Wg[f * 24 + j], fl[j], g);
                gate_ws[bf] = 1.0f / (1.0f + expf(-g));
            }
        }
        return;
    }

    int b = blk >> 6;
    int l0 = (blk & 63) << 6;
    int lane = tid & 63;
    int w = tid >> 6;
    int h_half = w >> 1;
    int l_q = w & 1;
    int ln15 = lane & 15, lq4 = lane >> 4;

    int lr0 = l0 + l_q * 32 + ln15;
    int lr1 = lr0 + 16;
    float mk0 = mask[(size_t)b * LL + lr0];
    float mk1 = mask[(size_t)b * LL + lr1];

    floatx4 acc[4][2];
#pragma unroll
    for (int i = 0; i < 4; ++i)
#pragma unroll
        for (int j = 0; j < 2; ++j) acc[i][j] = (floatx4){0.f, 0.f, 0.f, 0.f};

#pragma unroll
    for (int ks = 0; ks < 2; ++ks) {
        int c0 = ks * 32 + (lq4 << 3);
        short8 bf0, bf1;
        {
            const float* xp = x + ((size_t)b * LL + lr0) * CC + c0;
            float4 xa = *(const float4*)xp;
            float4 xb = *(const float4*)(xp + 4);
            bf0[0] = (short)f2b(xa.x * mk0); bf0[1] = (short)f2b(xa.y * mk0);
            bf0[2] = (short)f2b(xa.z * mk0); bf0[3] = (short)f2b(xa.w * mk0);
            bf0[4] = (short)f2b(xb.x * mk0); bf0[5] = (short)f2b(xb.y * mk0);
            bf0[6] = (short)f2b(xb.z * mk0); bf0[7] = (short)f2b(xb.w * mk0);
        }
        {
            const float* xp = x + ((size_t)b * LL + lr1) * CC + c0;
            float4 xa = *(const float4*)xp;
            float4 xb = *(const float4*)(xp + 4);
            bf1[0] = (short)f2b(xa.x * mk1); bf1[1] = (short)f2b(xa.y * mk1);
            bf1[2] = (short)f2b(xa.z * mk1); bf1[3] = (short)f2b(xa.w * mk1);
            bf1[4] = (short)f2b(xb.x * mk1); bf1[5] = (short)f2b(xb.y * mk1);
            bf1[6] = (short)f2b(xb.z * mk1); bf1[7] = (short)f2b(xb.w * mk1);
        }
        const float* wb = W_in + (size_t)(h_half * 64 + ln15) * CC + c0;
#pragma unroll
        for (int ht = 0; ht < 4; ++ht) {
            const float* wr = wb + (size_t)ht * 16 * CC;
            float4 wa = *(const float4*)wr;
            float4 wc = *(const float4*)(wr + 4);
            short8 af;
            af[0] = (short)f2b(wa.x); af[1] = (short)f2b(wa.y);
            af[2] = (short)f2b(wa.z); af[3] = (short)f2b(wa.w);
            af[4] = (short)f2b(wc.x); af[5] = (short)f2b(wc.y);
            af[6] = (short)f2b(wc.z); af[7] = (short)f2b(wc.w);
            acc[ht][0] = __builtin_amdgcn_mfma_f32_16x16x32_bf16(bf0, af, acc[ht][0], 0, 0, 0);
            acc[ht][1] = __builtin_amdgcn_mfma_f32_16x16x32_bf16(bf1, af, acc[ht][1], 0, 0, 0);
        }
    }

#pragma unroll
    for (int ht = 0; ht < 4; ++ht) {
        int h = h_half * 64 + ht * 16 + ln15;        // fixed per lane
        float bi = b_in[h];
        unsigned short* zr = z_bf + ((size_t)(b * HD + h)) * LL;
#pragma unroll
        for (int j = 0; j < 2; ++j) {
            int lbase = l0 + l_q * 32 + j * 16 + (lq4 << 2);
            ushort4 o;
            o.x = f2b(acc[ht][j][0] + bi);
            o.y = f2b(acc[ht][j][1] + bi);
            o.z = f2b(acc[ht][j][2] + bi);
            o.w = f2b(acc[ht][j][3] + bi);
            *(ushort4*)(zr + lbase) = o;
        }
    }
}

// ---------------- wavelet helpers ----------------

__device__ __forceinline__ void analysis_step(const float* __restrict__ src,
                                              float* __restrict__ lo_dst,
                                              float* __restrict__ hi_dst,
                                              int half, int tid) {
    int len = half << 1;
    for (int q = tid; q < (half >> 2); q += 256) {
        int n0 = q << 2;
        float lo[4], hi[4];
        if (n0 + 4 == half) {                       // only quad that wraps
#pragma unroll
            for (int i = 0; i < 4; ++i) {
                float l = 0.f, hh = 0.f;
#pragma unroll
                for (int k = 0; k < 8; ++k) {
                    float v = src[(2 * (n0 + i) + k) & (len - 1)];
                    l = fmaf(c_lo[k], v, l);
                    hh = fmaf(c_hi[k], v, hh);
                }
                lo[i] = l; hi[i] = hh;
            }
        } else {
            float sv[16];
            const float* sp = src + (n0 << 1);
            *(float4*)&sv[0]  = *(const float4*)(sp);
            *(float4*)&sv[4]  = *(const float4*)(sp + 4);
            *(float4*)&sv[8]  = *(const float4*)(sp + 8);
            *(float4*)&sv[12] = *(const float4*)(sp + 12);
#pragma unroll
            for (int i = 0; i < 4; ++i) {
                float l = 0.f, hh = 0.f;
#pragma unroll
                for (int k = 0; k < 8; ++k) {
                    l = fmaf(c_lo[k], sv[2 * i + k], l);
                    hh = fmaf(c_hi[k], sv[2 * i + k], hh);
                }
                lo[i] = l; hi[i] = hh;
            }
        }
        *(float4*)&lo_dst[n0] = make_float4(lo[0], lo[1], lo[2], lo[3]);
        *(float4*)&hi_dst[n0] = make_float4(hi[0], hi[1], hi[2], hi[3]);
    }
}

__device__ __forceinline__ void synth_oct(const float* __restrict__ A,
                                          const float* __restrict__ D,
                                          int m0, int half, float* ov) {
    if (m0 == 0) {                                  // only oct that wraps (backward)
        int mask2 = (half << 1) - 1;
#pragma unroll
        for (int t = 0; t < 8; ++t) {
            int par = t & 1;
            float s = 0.f;
#pragma unroll
            for (int j = 0; j < 4; ++j) {
                int k = 2 * j + par;
                int idx = ((t - k) & mask2) >> 1;
                s = fmaf(c_lo[k], A[idx], s);
                s = fmaf(c_hi[k], D[idx], s);
            }
            ov[t] = s;
        }
    } else {
        float av[8], dv[8];
        *(float4*)&av[0] = *(const float4*)(A + m0 - 4);
        *(float4*)&av[4] = *(const float4*)(A + m0);
        *(float4*)&dv[0] = *(const float4*)(D + m0 - 4);
        *(float4*)&dv[4] = *(const float4*)(D + m0);
#pragma unroll
        for (int t = 0; t < 4; ++t) {
            float e = 0.f, o = 0.f;
#pragma unroll
            for (int j = 0; j < 4; ++j) {
                float xa = av[t + 4 - j], xd = dv[t + 4 - j];
                e = fmaf(c_lo[2 * j], xa, e);     e = fmaf(c_hi[2 * j], xd, e);
                o = fmaf(c_lo[2 * j + 1], xa, o); o = fmaf(c_hi[2 * j + 1], xd, o);
            }
            ov[2 * t] = e;
            ov[2 * t + 1] = o;
        }
    }
}

__device__ __forceinline__ void synth_step(const float* __restrict__ A,
                                           const float* __restrict__ D,
                                           float* __restrict__ dst,
                                           int half, int tid) {
    for (int q = tid; q < (half >> 2); q += 256) {
        int m0 = q << 2;
        int i0 = m0 << 1;
        float ov[8];
        synth_oct(A, D, m0, half, ov);
        *(float4*)&dst[i0]     = make_float4(ov[0], ov[1], ov[2], ov[3]);
        *(float4*)&dst[i0 + 4] = make_float4(ov[4], ov[5], ov[6], ov[7]);
    }
}

// ---------------- per-row wavelet: 24 KB LDS, direct-global z reads ----------------

__global__ __launch_bounds__(256) void wavelet_kernel(const unsigned short* __restrict__ z_bf,
                                                      unsigned short* __restrict__ s_bf,
                                                      const float* __restrict__ film_ws,
                                                      const float* __restrict__ gate_ws,
                                                      const float* __restrict__ lam_raw,
                                                      float* __restrict__ lam_ws) {
    __shared__ float d1[2048];
    __shared__ float d2[1024];
    __shared__ float Aq[2048];
    __shared__ float Bq[1024];

    int blk = blockIdx.x;
    int b = blk >> 7;
    int h = blk & 127;
    int tid = threadIdx.x;
    const unsigned short* zg = z_bf + ((size_t)(b * HD + h)) * LL;
    unsigned short* sg = s_bf + ((size_t)(b * HD + h)) * LL;

    for (int q = tid; q < 512; q += 256) {
        int n0 = q << 2;
        float sv[16];
        if (n0 == 2044) {                           // the wrapping quad
#pragma unroll
            for (int j = 0; j < 14; ++j)
                sv[j] = b2f(zg[(2 * n0 + j) & 4095]);
            sv[14] = 0.f; sv[15] = 0.f;
        } else {
            ushort8 va = *(const ushort8*)(zg + (n0 << 1));
            ushort8 vb = *(const ushort8*)(zg + (n0 << 1) + 8);
#pragma unroll
            for (int j = 0; j < 8; ++j) {
                sv[j]     = b2f(va[j]);
                sv[8 + j] = b2f(vb[j]);
            }
        }
        float lo[4], hi[4];
#pragma unroll
        for (int i = 0; i < 4; ++i) {
            float l = 0.f, hh = 0.f;
#pragma unroll
            for (int k = 0; k < 8; ++k) {
                l = fmaf(c_lo[k], sv[2 * i + k], l);
                hh = fmaf(c_hi[k], sv[2 * i + k], hh);
            }
            lo[i] = l; hi[i] = hh;
        }
        *(float4*)&Aq[n0] = make_float4(lo[0], lo[1], lo[2], lo[3]);
        *(float4*)&d1[n0] = make_float4(hi[0], hi[1], hi[2], hi[3]);
    }
    __syncthreads();
    analysis_step(Aq, Bq, d2, 1024, tid);        // L2
    __syncthreads();
    analysis_step(Bq, Aq, Aq + 512, 512, tid);   // L3
    __syncthreads();

    float sc0, sh0, sc1, sh1, sc2, sh2, sc3, sh3;
    {
        int base = b * 4;
#define FILM_COEF(bd, SC, SH)                                              \
        {   float ga = film_ws[((size_t)(base + bd)) * 256 + h];           \
            float be = film_ws[((size_t)(base + bd)) * 256 + 128 + h];     \
            float gt = gate_ws[base + bd];                                 \
            SC = 1.0f + gt * ga; SH = gt * be; }
        FILM_COEF(0, sc0, sh0) FILM_COEF(1, sc1, sh1)
        FILM_COEF(2, sc2, sh2) FILM_COEF(3, sc3, sh3)
#undef FILM_COEF
    }

    float* p0 = &Aq[tid << 2];
    float* p1 = &d1[tid << 2];
    float* p2 = &d1[1024 + (tid << 2)];
    float* p3 = &d2[tid << 2];
    bool lowhalf = (tid < 128);
    float scA = lowhalf ? sc0 : sc3, shA = lowhalf ? sh0 : sh3;

    float4 f0 = *(float4*)p0, f1 = *(float4*)p1, f2v = *(float4*)p2, f3 = *(float4*)p3;
#define FILMV(V, SC, SH)                                                   \
    { V.x = fmaf(V.x, SC, SH); V.y = fmaf(V.y, SC, SH);                    \
      V.z = fmaf(V.z, SC, SH); V.w = fmaf(V.w, SC, SH); }
    FILMV(f0, scA, shA) FILMV(f1, sc1, sh1) FILMV(f2v, sc1, sh1) FILMV(f3, sc2, sh2)
#undef FILMV
    float sA = fabsf(f0.x) + fabsf(f0.y) + fabsf(f0.z) + fabsf(f0.w);
    float s1 = fabsf(f1.x) + fabsf(f1.y) + fabsf(f1.z) + fabsf(f1.w)
             + fabsf(f2v.x) + fabsf(f2v.y) + fabsf(f2v.z) + fabsf(f2v.w);
    float s2 = fabsf(f3.x) + fabsf(f3.y) + fabsf(f3.z) + fabsf(f3.w);
#pragma unroll
    for (int off = 32; off > 0; off >>= 1) {
        sA += __shfl_xor(sA, off);
        s1 += __shfl_xor(s1, off);
        s2 += __shfl_xor(s2, off);
    }
    if ((tid & 63) == 0)
        ((float4*)Bq)[tid >> 6] = make_float4(lowhalf ? sA : 0.f, s1, s2,
                                              lowhalf ? 0.f : sA);
    __syncthreads();
    float4 r0 = ((const float4*)Bq)[0];
    float4 r1 = ((const float4*)Bq)[1];
    float4 r2 = ((const float4*)Bq)[2];
    float4 r3 = ((const float4*)Bq)[3];
    float lam0 = log1pf(expf(lam_raw[0])) * ((r0.x + r1.x + r2.x + r3.x) * (1.0f / 512.f));
    float lam1 = log1pf(expf(lam_raw[1])) * ((r0.y + r1.y + r2.y + r3.y) * (1.0f / 2048.f));
    float lam2 = log1pf(expf(lam_raw[2])) * ((r0.z + r1.z + r2.z + r3.z) * (1.0f / 1024.f));
    float lam3 = log1pf(expf(lam_raw[3])) * ((r0.w + r1.w + r2.w + r3.w) * (1.0f / 512.f));
    if (tid < 4) {
        float lam = (tid == 0) ? lam0 : (tid == 1) ? lam1 : (tid == 2) ? lam2 : lam3;
        lam_ws[((size_t)(b * 4 + tid)) * 128 + h] = lam;
    }
    float lamA = lowhalf ? lam0 : lam3;
#define THRV(V, LAM)                                                       \
    { float a;                                                             \
      a = fabsf(V.x) - (LAM); V.x = (a > 0.f) ? copysignf(a, V.x) : 0.f;   \
      a = fabsf(V.y) - (LAM); V.y = (a > 0.f) ? copysignf(a, V.y) : 0.f;   \
      a = fabsf(V.z) - (LAM); V.z = (a > 0.f) ? copysignf(a, V.z) : 0.f;   \
      a = fabsf(V.w) - (LAM); V.w = (a > 0.f) ? copysignf(a, V.w) : 0.f; }
    THRV(f0, lamA) THRV(f1, lam1) THRV(f2v, lam1) THRV(f3, lam2)
#undef THRV
    *(float4*)p0 = f0; *(float4*)p1 = f1; *(float4*)p2 = f2v; *(float4*)p3 = f3;
    __syncthreads();

    synth_step(Aq, Aq + 512, Bq, 512, tid);      // R1 -> Bq[0:1024]
    __syncthreads();
    synth_step(Bq, d2, Aq, 1024, tid);           // R2 -> Aq[0:2048]
    __syncthreads();
    for (int q = tid; q < 512; q += 256) {       // R3 + residual + store
        int m0 = q << 2;
        int i0 = m0 << 1;
        float ov[8];
        synth_oct(Aq, d1, m0, 2048, ov);
        ushort8 zin = *(const ushort8*)(zg + i0);
        ushort8 o8;
#pragma unroll
        for (int t = 0; t < 8; ++t) o8[t] = f2b(ov[t] + b2f(zin[t]));
        *(ushort8*)(sg + i0) = o8;
    }
}

// ---------------- mix: operand-swapped MFMA -> D[g][l], float4 out stores ----------------

union U32x4S8 { unsigned int u[4]; short8 s; };

__global__ __launch_bounds__(256) void mix_kernel(const unsigned short* __restrict__ s_bf,
                                                  const unsigned short* __restrict__ Bmix,
                                                  const float* __restrict__ b_mix,
                                                  const float* __restrict__ mask,
                                                  float* __restrict__ out,
                                                  float* __restrict__ pool_part) {
    __shared__ unsigned int T[HD * 32];   // 16 KB, [h][lp ^ (h&31)]
    __shared__ float pbuf[2][HD];

    int blk = blockIdx.x;
    int b = blk >> 6;
    int lt64 = blk & 63;
    int l0 = lt64 << 6;
    int tid = threadIdx.x;
    int lane = tid & 63;
    int w = tid >> 6;
    int l_half = w >> 1, g_half = w & 1;
    int ln15 = lane & 15, lq4 = lane >> 4;

    {
        const unsigned int* src = (const unsigned int*)s_bf;
#pragma unroll
        for (int r = 0; r < 4; ++r) {
            int q = (r << 8) + tid;              // 0..1023
            int hh = q >> 3;                     // 0..127
            int k = q & 7;                       // 16B chunk
            uint4 v = *(const uint4*)(src + (size_t)(b * HD + hh) * (LL / 2) +
                                      (l0 >> 1) + (k << 2));
            int sw = hh & 31;
            unsigned int* tp = T + hh * 32;
            tp[((k << 2) + 0) ^ sw] = v.x;
            tp[((k << 2) + 1) ^ sw] = v.y;
            tp[((k << 2) + 2) ^ sw] = v.z;
            tp[((k << 2) + 3) ^ sw] = v.w;
        }
    }
    __syncthreads();

    floatx4 acc[2][4];
#pragma unroll
    for (int i = 0; i < 2; ++i)
#pragma unroll
        for (int j = 0; j < 4; ++j) acc[i][j] = (floatx4){0.f, 0.f, 0.f, 0.f};

    const unsigned short* Bb = Bmix + (g_half * 64 + ln15) * 8;

#pragma unroll 2
    for (int ks = 0; ks < 4; ++ks) {
        int koct = ks * 4 + lq4;
        short8 a[2], bb[4];
#pragma unroll
        for (int lt = 0; lt < 2; ++lt) {
            int l_loc = l_half * 32 + lt * 16 + ln15;
            int lp = l_loc >> 1;
            int odd = l_loc & 1;
            U32x4S8 cv;
#pragma unroll
            for (int qq = 0; qq < 4; ++qq) {
                int h0 = koct * 8 + 2 * qq;
                unsigned int w0 = T[h0 * 32 + (lp ^ (h0 & 31))];
                unsigned int w1 = T[(h0 + 1) * 32 + (lp ^ ((h0 + 1) & 31))];
                unsigned int e0 = odd ? (w0 >> 16) : (w0 & 0xffffu);
                unsigned int e1 = odd ? (w1 >> 16) : (w1 & 0xffffu);
                cv.u[qq] = e0 | (e1 << 16);
            }
            a[lt] = cv.s;
        }
#pragma unroll
        for (int gt = 0; gt < 4; ++gt)
            bb[gt] = *(const short8*)(Bb + (size_t)koct * 1024 + gt * 128);
        // swapped operands: D[g][l]
#pragma unroll
        for (int lt = 0; lt < 2; ++lt)
#pragma unroll
            for (int gt = 0; gt < 4; ++gt)
                acc[lt][gt] = __builtin_amdgcn_mfma_f32_16x16x32_bf16(bb[gt], a[lt], acc[lt][gt], 0, 0, 0);
    }

    // epilogue: lane = fixed l (ln15), regs = 4 consecutive g
    float4 pacc4[4];
#pragma unroll
    for (int gt = 0; gt < 4; ++gt) pacc4[gt] = make_float4(0.f, 0.f, 0.f, 0.f);

#pragma unroll
    for (int lt = 0; lt < 2; ++lt) {
        int l = l0 + l_half * 32 + lt * 16 + ln15;
        float mkv = mask[(size_t)b * LL + l];
        float* orow = out + ((size_t)b * LL + l) * HD;
#pragma unroll
        for (int gt = 0; gt < 4; ++gt) {
            int g0q = g_half * 64 + gt * 16 + (lq4 << 2);
            float4 bm = *(const float4*)&b_mix[g0q];
            float4 v;
            v.x = gelu_fast(acc[lt][gt][0] + bm.x) * mkv;
            v.y = gelu_fast(acc[lt][gt][1] + bm.y) * mkv;
            v.z = gelu_fast(acc[lt][gt][2] + bm.z) * mkv;
            v.w = gelu_fast(acc[lt][gt][3] + bm.w) * mkv;
            *(float4*)&orow[g0q] = v;
            pacc4[gt].x = fmaf(v.x, mkv, pacc4[gt].x);
            pacc4[gt].y = fmaf(v.y, mkv, pacc4[gt].y);
            pacc4[gt].z = fmaf(v.z, mkv, pacc4[gt].z);
            pacc4[gt].w = fmaf(v.w, mkv, pacc4[gt].w);
        }
    }
    // reduce over the 16 l-lanes (ln15 groups)
#pragma unroll
    for (int gt = 0; gt < 4; ++gt) {
#pragma unroll
        for (int off = 1; off <= 8; off <<= 1) {
            pacc4[gt].x += __shfl_xor(pacc4[gt].x, off);
            pacc4[gt].y += __shfl_xor(pacc4[gt].y, off);
            pacc4[gt].z += __shfl_xor(pacc4[gt].z, off);
            pacc4[gt].w += __shfl_xor(pacc4[gt].w, off);
        }
    }
    if (ln15 == 0) {
#pragma unroll
        for (int gt = 0; gt < 4; ++gt)
            *(float4*)&pbuf[l_half][g_half * 64 + gt * 16 + (lq4 << 2)] = pacc4[gt];
    }
    __syncthreads();
    if (tid < HD)
        pool_part[((size_t)(b * 64 + lt64)) * HD + tid] = pbuf[0][tid] + pbuf[1][tid];
}

// ---------------- finalize: denom + pool + lam mean/max ----------------

__global__ void finalize_kernel(const float* __restrict__ pool_part,
                                const float* __restrict__ mask,
                                const float* __restrict__ lam_ws,
                                float* __restrict__ d_out) {
    const size_t OUT1 = (size_t)BB * LL * HD;
    const size_t OUT2 = OUT1 + (size_t)BB * HD;
    const size_t OUT3 = OUT2 + BB;
    int b = blockIdx.x, tid = threadIdx.x;
    __shared__ float rsum[256], rmax[256];
    __shared__ float dsh;

    float ms = 0.f;
    const float4* mp = (const float4*)(mask + (size_t)b * LL);
    for (int i = tid; i < LL / 4; i += 256) {
        float4 m = mp[i];
        ms += m.x + m.y + m.z + m.w;
    }
    rsum[tid] = ms; __syncthreads();
    for (int st = 128; st > 0; st >>= 1) {
        if (tid < st) rsum[tid] += rsum[tid + st];
        __syncthreads();
    }
    if (tid == 0) dsh = fmaxf(rsum[0], 1.0f);
    __syncthreads();
    float denom = dsh;
    __syncthreads();

    // pool: 256 threads = 128 h x 2 halves (coalesced h-major reads, 32-deep chains)
    {
        int hh = tid & 127, half = tid >> 7;
        float s = 0.f;
        for (int blk = half * 32; blk < half * 32 + 32; ++blk)
            s += pool_part[((size_t)(b * 64 + blk)) * HD + hh];
        rsum[tid] = s;
        __syncthreads();
        if (tid < 128)
            d_out[OUT1 + (size_t)b * HD + tid] = (rsum[tid] + rsum[tid + 128]) / denom;
        __syncthreads();
    }

    float v0 = lam_ws[(size_t)b * 512 + tid];
    float v1 = lam_ws[(size_t)b * 512 + 256 + tid];
    rsum[tid] = v0 + v1;
    rmax[tid] = fmaxf(v0, v1);
    __syncthreads();
    for (int st = 128; st > 0; st >>= 1) {
        if (tid < st) {
            rsum[tid] += rsum[tid + st];
            rmax[tid] = fmaxf(rmax[tid], rmax[tid + st]);
        }
        __syncthreads();
    }
    if (tid == 0) {
        d_out[OUT2 + b] = rsum[0] / 512.0f;
        d_out[OUT3 + b] = rmax[0];
    }
}

// ---------------- launch ----------------

extern "C" void kernel_launch(void* const* d_in, const int* in_sizes, int n_in,
                              void* d_out, int out_size, void* d_ws, size_t ws_size,
                              hipStream_t stream) {
    (void)in_sizes; (void)n_in; (void)out_size; (void)ws_size;
    const float* x      = (const float*)d_in[0];
    const float* mask   = (const float*)d_in[1];
    const float* flow   = (const float*)d_in[2];
    const float* W_in   = (const float*)d_in[3];
    const float* b_in   = (const float*)d_in[4];
    const float* W_mix  = (const float*)d_in[5];
    const float* b_mix  = (const float*)d_in[6];
    const float* lam_raw= (const float*)d_in[7];
    const float* Wgb    = (const float*)d_in[8];
    const float* bgb    = (const float*)d_in[9];
    const float* Wg     = (const float*)d_in[10];
    const float* bg     = (const float*)d_in[11];

    unsigned short* z_bf = (unsigned short*)d_ws;                 // 8388608 ushort
    unsigned short* s_bf = z_bf + (size_t)BB * HD * LL;           // 8388608 ushort
    float* film_ws   = (float*)(s_bf + (size_t)BB * HD * LL);     // 16384
    float* gate_ws   = film_ws + BB * 4 * 256;                    // 64
    float* lam_ws    = gate_ws + 64;                              // 8192
    float* pool_part = lam_ws + BB * 4 * 128;                     // 16*64*128 = 131072
    unsigned short* Bmix = (unsigned short*)(pool_part + BB * 64 * HD);  // 16384 ushort

    float* out = (float*)d_out;

    hipLaunchKernelGGL(zproj_kernel, dim3(BB * 64 + 128), dim3(256), 0, stream,
                       x, mask, W_in, b_in, z_bf,
                       W_mix, Bmix, flow, Wgb, bgb, Wg, bg, film_ws, gate_ws);
    hipLaunchKernelGGL(wavelet_kernel, dim3(BB * HD), dim3(256), 0, stream,
                       z_bf, s_bf, film_ws, gate_ws, lam_raw, lam_ws);
    hipLaunchKernelGGL(mix_kernel, dim3(BB * (LL / 64)), dim3(256), 0, stream,
                       s_bf, Bmix, b_mix, mask, out, pool_part);
    hipLaunchKernelGGL(finalize_kernel, dim3(BB), dim3(256), 0, stream,
                       pool_part, mask, lam_ws, out);
}

// Round 13
// 64.740 us; speedup vs baseline: 2.8836x; 1.0293x over previous
//
#include <hip/hip_runtime.h>
#include <math.h>

#define BB 16
#define LL 4096
#define CC 64
#define HD 128

typedef __attribute__((ext_vector_type(8))) short short8;
typedef __attribute__((ext_vector_type(8))) unsigned short ushort8;
typedef __attribute__((ext_vector_type(4))) float floatx4;

__constant__ float c_lo[8] = {
    -0.010597401784997278f, 0.032883011666982945f, 0.030841381835986965f,
    -0.18703481171888114f, -0.02798376941698385f, 0.6308807679295904f,
    0.7148465705525415f, 0.23037781330885523f};
__constant__ float c_hi[8] = {
    -0.23037781330885523f, 0.7148465705525415f, -0.6308807679295904f,
    -0.02798376941698385f, 0.18703481171888114f, 0.030841381835986965f,
    -0.032883011666982945f, -0.010597401784997278f};

// tanh-GELU in sigmoid form, max abs err vs erf-GELU ~3e-4
__device__ __forceinline__ float gelu_fast(float x) {
    float u = x * fmaf(0.044715f * x, x, 1.0f) * 1.5957691216057308f;
    return x / (1.0f + __expf(-u));
}
__device__ __forceinline__ unsigned short f2b(float f) {   // f32 -> bf16 RNE
    unsigned int u = __float_as_uint(f);
    u = u + 0x7FFFu + ((u >> 16) & 1u);
    return (unsigned short)(u >> 16);
}
__device__ __forceinline__ float b2f(unsigned short s) {
    return __uint_as_float(((unsigned int)s) << 16);
}

// ---------------- zproj (+ fused pack blocks for Bmix / FiLM) ----------------
// W_in staged once per block into chunk-swizzled bf16 LDS (no per-thread reconvert).
// Operand-swapped MFMA: D[l][h] -> 8x ushort4 stores.

__global__ __launch_bounds__(256) void zproj_kernel(
    const float* __restrict__ x, const float* __restrict__ mask,
    const float* __restrict__ W_in, const float* __restrict__ b_in,
    unsigned short* __restrict__ z_bf,
    const float* __restrict__ W_mix, unsigned short* __restrict__ Bmix,
    const float* __restrict__ flow, const float* __restrict__ Wgb,
    const float* __restrict__ bgb, const float* __restrict__ Wg,
    const float* __restrict__ bg, float* __restrict__ film_ws,
    float* __restrict__ gate_ws) {
    __shared__ unsigned short Wl[HD * CC];   // 16 KB bf16 W, chunk ^ (h&7) swizzle
    int blk = blockIdx.x;
    int tid = threadIdx.x;

    if (blk >= BB * 64) {
        int e = blk - BB * 64;
        if (e < 64) {                               // Bmix pack: idx = ((h>>3)*128+g)*8+(h&7)
            int q = e * 256 + tid;                  // 16384
            int g = (q >> 3) & 127;
            int h = ((q >> 10) << 3) | (q & 7);
            Bmix[q] = f2b(W_mix[g * HD + h]);
        } else {                                    // FiLM
            int bf = e - 64;                        // b*4 + f
            int f = bf & 3;
            int b = bf >> 2;
            const float* fl = flow + b * 24;
            const float* wrow = Wgb + ((size_t)(f * 256 + tid)) * 24;
            float acc = bgb[f * 256 + tid];
#pragma unroll
            for (int j = 0; j < 24; ++j) acc = fmaf(wrow[j], fl[j], acc);
            film_ws[(size_t)bf * 256 + tid] = acc;
            if (tid == 0) {
                float g = bg[f];
#pragma unroll
                for (int j = 0; j < 24; ++j) g = fmaf(Wg[f * 24 + j], fl[j], g);
                gate_ws[bf] = 1.0f / (1.0f + expf(-g));
            }
        }
        return;
    }

    // stage W_in as bf16, 4 chunks (of 8 bf16) per thread
#pragma unroll
    for (int j = 0; j < 4; ++j) {
        int ci = (tid << 2) + j;           // 0..1023
        int h = ci >> 3, cc = ci & 7;
        const float* wr = W_in + (size_t)h * CC + (cc << 3);
        float4 wa = *(const float4*)wr;
        float4 wb = *(const float4*)(wr + 4);
        short8 sf;
        sf[0] = (short)f2b(wa.x); sf[1] = (short)f2b(wa.y);
        sf[2] = (short)f2b(wa.z); sf[3] = (short)f2b(wa.w);
        sf[4] = (short)f2b(wb.x); sf[5] = (short)f2b(wb.y);
        sf[6] = (short)f2b(wb.z); sf[7] = (short)f2b(wb.w);
        *(short8*)&Wl[(((h << 3) + (cc ^ (h & 7))) << 3)] = sf;
    }

    int b = blk >> 6;
    int l0 = (blk & 63) << 6;
    int lane = tid & 63;
    int w = tid >> 6;
    int h_half = w >> 1;
    int l_q = w & 1;
    int ln15 = lane & 15, lq4 = lane >> 4;
    int hp = ln15 & 7;

    int lr0 = l0 + l_q * 32 + ln15;
    int lr1 = lr0 + 16;
    float mk0 = mask[(size_t)b * LL + lr0];
    float mk1 = mask[(size_t)b * LL + lr1];

    floatx4 acc[4][2];
#pragma unroll
    for (int i = 0; i < 4; ++i)
#pragma unroll
        for (int j = 0; j < 2; ++j) acc[i][j] = (floatx4){0.f, 0.f, 0.f, 0.f};

    __syncthreads();

#pragma unroll
    for (int ks = 0; ks < 2; ++ks) {
        int c0 = ks * 32 + (lq4 << 3);
        short8 bf0, bf1;
        {
            const float* xp = x + ((size_t)b * LL + lr0) * CC + c0;
            float4 xa = *(const float4*)xp;
            float4 xb = *(const float4*)(xp + 4);
            bf0[0] = (short)f2b(xa.x * mk0); bf0[1] = (short)f2b(xa.y * mk0);
            bf0[2] = (short)f2b(xa.z * mk0); bf0[3] = (short)f2b(xa.w * mk0);
            bf0[4] = (short)f2b(xb.x * mk0); bf0[5] = (short)f2b(xb.y * mk0);
            bf0[6] = (short)f2b(xb.z * mk0); bf0[7] = (short)f2b(xb.w * mk0);
        }
        {
            const float* xp = x + ((size_t)b * LL + lr1) * CC + c0;
            float4 xa = *(const float4*)xp;
            float4 xb = *(const float4*)(xp + 4);
            bf1[0] = (short)f2b(xa.x * mk1); bf1[1] = (short)f2b(xa.y * mk1);
            bf1[2] = (short)f2b(xa.z * mk1); bf1[3] = (short)f2b(xa.w * mk1);
            bf1[4] = (short)f2b(xb.x * mk1); bf1[5] = (short)f2b(xb.y * mk1);
            bf1[6] = (short)f2b(xb.z * mk1); bf1[7] = (short)f2b(xb.w * mk1);
        }
        int cc = (ks << 2) + lq4;          // k-chunk index, matches c0
#pragma unroll
        for (int ht = 0; ht < 4; ++ht) {
            int hrow = h_half * 64 + ht * 16 + ln15;
            short8 af = *(const short8*)&Wl[(((hrow << 3) + (cc ^ hp)) << 3)];
            acc[ht][0] = __builtin_amdgcn_mfma_f32_16x16x32_bf16(bf0, af, acc[ht][0], 0, 0, 0);
            acc[ht][1] = __builtin_amdgcn_mfma_f32_16x16x32_bf16(bf1, af, acc[ht][1], 0, 0, 0);
        }
    }

#pragma unroll
    for (int ht = 0; ht < 4; ++ht) {
        int h = h_half * 64 + ht * 16 + ln15;        // fixed per lane
        float bi = b_in[h];
        unsigned short* zr = z_bf + ((size_t)(b * HD + h)) * LL;
#pragma unroll
        for (int j = 0; j < 2; ++j) {
            int lbase = l0 + l_q * 32 + j * 16 + (lq4 << 2);
            ushort4 o;
            o.x = f2b(acc[ht][j][0] + bi);
            o.y = f2b(acc[ht][j][1] + bi);
            o.z = f2b(acc[ht][j][2] + bi);
            o.w = f2b(acc[ht][j][3] + bi);
            *(ushort4*)(zr + lbase) = o;
        }
    }
}

// ---------------- wavelet helpers ----------------

__device__ __forceinline__ void analysis_step(const float* __restrict__ src,
                                              float* __restrict__ lo_dst,
                                              float* __restrict__ hi_dst,
                                              int half, int tid) {
    int len = half << 1;
    for (int q = tid; q < (half >> 2); q += 256) {
        int n0 = q << 2;
        float lo[4], hi[4];
        if (n0 + 4 == half) {                       // only quad that wraps
#pragma unroll
            for (int i = 0; i < 4; ++i) {
                float l = 0.f, hh = 0.f;
#pragma unroll
                for (int k = 0; k < 8; ++k) {
                    float v = src[(2 * (n0 + i) + k) & (len - 1)];
                    l = fmaf(c_lo[k], v, l);
                    hh = fmaf(c_hi[k], v, hh);
                }
                lo[i] = l; hi[i] = hh;
            }
        } else {
            float sv[16];
            const float* sp = src + (n0 << 1);
            *(float4*)&sv[0]  = *(const float4*)(sp);
            *(float4*)&sv[4]  = *(const float4*)(sp + 4);
            *(float4*)&sv[8]  = *(const float4*)(sp + 8);
            *(float4*)&sv[12] = *(const float4*)(sp + 12);
#pragma unroll
            for (int i = 0; i < 4; ++i) {
                float l = 0.f, hh = 0.f;
#pragma unroll
                for (int k = 0; k < 8; ++k) {
                    l = fmaf(c_lo[k], sv[2 * i + k], l);
                    hh = fmaf(c_hi[k], sv[2 * i + k], hh);
                }
                lo[i] = l; hi[i] = hh;
            }
        }
        *(float4*)&lo_dst[n0] = make_float4(lo[0], lo[1], lo[2], lo[3]);
        *(float4*)&hi_dst[n0] = make_float4(hi[0], hi[1], hi[2], hi[3]);
    }
}

__device__ __forceinline__ void synth_oct(const float* __restrict__ A,
                                          const float* __restrict__ D,
                                          int m0, int half, float* ov) {
    if (m0 == 0) {                                  // only oct that wraps (backward)
        int mask2 = (half << 1) - 1;
#pragma unroll
        for (int t = 0; t < 8; ++t) {
            int par = t & 1;
            float s = 0.f;
#pragma unroll
            for (int j = 0; j < 4; ++j) {
                int k = 2 * j + par;
                int idx = ((t - k) & mask2) >> 1;
                s = fmaf(c_lo[k], A[idx], s);
                s = fmaf(c_hi[k], D[idx], s);
            }
            ov[t] = s;
        }
    } else {
        float av[8], dv[8];
        *(float4*)&av[0] = *(const float4*)(A + m0 - 4);
        *(float4*)&av[4] = *(const float4*)(A + m0);
        *(float4*)&dv[0] = *(const float4*)(D + m0 - 4);
        *(float4*)&dv[4] = *(const float4*)(D + m0);
#pragma unroll
        for (int t = 0; t < 4; ++t) {
            float e = 0.f, o = 0.f;
#pragma unroll
            for (int j = 0; j < 4; ++j) {
                float xa = av[t + 4 - j], xd = dv[t + 4 - j];
                e = fmaf(c_lo[2 * j], xa, e);     e = fmaf(c_hi[2 * j], xd, e);
                o = fmaf(c_lo[2 * j + 1], xa, o); o = fmaf(c_hi[2 * j + 1], xd, o);
            }
            ov[2 * t] = e;
            ov[2 * t + 1] = o;
        }
    }
}

__device__ __forceinline__ void synth_step(const float* __restrict__ A,
                                           const float* __restrict__ D,
                                           float* __restrict__ dst,
                                           int half, int tid) {
    for (int q = tid; q < (half >> 2); q += 256) {
        int m0 = q << 2;
        int i0 = m0 << 1;
        float ov[8];
        synth_oct(A, D, m0, half, ov);
        *(float4*)&dst[i0]     = make_float4(ov[0], ov[1], ov[2], ov[3]);
        *(float4*)&dst[i0 + 4] = make_float4(ov[4], ov[5], ov[6], ov[7]);
    }
}

// ---------------- per-row wavelet: 24 KB LDS, direct-global z reads ----------------

__global__ __launch_bounds__(256) void wavelet_kernel(const unsigned short* __restrict__ z_bf,
                                                      unsigned short* __restrict__ s_bf,
                                                      const float* __restrict__ film_ws,
                                                      const float* __restrict__ gate_ws,
                                                      const float* __restrict__ lam_raw,
                                                      float* __restrict__ lam_ws) {
    __shared__ float d1[2048];
    __shared__ float d2[1024];
    __shared__ float Aq[2048];
    __shared__ float Bq[1024];

    int blk = blockIdx.x;
    int b = blk >> 7;
    int h = blk & 127;
    int tid = threadIdx.x;
    const unsigned short* zg = z_bf + ((size_t)(b * HD + h)) * LL;
    unsigned short* sg = s_bf + ((size_t)(b * HD + h)) * LL;

    for (int q = tid; q < 512; q += 256) {
        int n0 = q << 2;
        float sv[16];
        if (n0 == 2044) {                           // the wrapping quad
#pragma unroll
            for (int j = 0; j < 14; ++j)
                sv[j] = b2f(zg[(2 * n0 + j) & 4095]);
            sv[14] = 0.f; sv[15] = 0.f;
        } else {
            ushort8 va = *(const ushort8*)(zg + (n0 << 1));
            ushort8 vb = *(const ushort8*)(zg + (n0 << 1) + 8);
#pragma unroll
            for (int j = 0; j < 8; ++j) {
                sv[j]     = b2f(va[j]);
                sv[8 + j] = b2f(vb[j]);
            }
        }
        float lo[4], hi[4];
#pragma unroll
        for (int i = 0; i < 4; ++i) {
            float l = 0.f, hh = 0.f;
#pragma unroll
            for (int k = 0; k < 8; ++k) {
                l = fmaf(c_lo[k], sv[2 * i + k], l);
                hh = fmaf(c_hi[k], sv[2 * i + k], hh);
            }
            lo[i] = l; hi[i] = hh;
        }
        *(float4*)&Aq[n0] = make_float4(lo[0], lo[1], lo[2], lo[3]);
        *(float4*)&d1[n0] = make_float4(hi[0], hi[1], hi[2], hi[3]);
    }
    __syncthreads();
    analysis_step(Aq, Bq, d2, 1024, tid);        // L2
    __syncthreads();
    analysis_step(Bq, Aq, Aq + 512, 512, tid);   // L3
    __syncthreads();

    float sc0, sh0, sc1, sh1, sc2, sh2, sc3, sh3;
    {
        int base = b * 4;
#define FILM_COEF(bd, SC, SH)                                              \
        {   float ga = film_ws[((size_t)(base + bd)) * 256 + h];           \
            float be = film_ws[((size_t)(base + bd)) * 256 + 128 + h];     \
            float gt = gate_ws[base + bd];                                 \
            SC = 1.0f + gt * ga; SH = gt * be; }
        FILM_COEF(0, sc0, sh0) FILM_COEF(1, sc1, sh1)
        FILM_COEF(2, sc2, sh2) FILM_COEF(3, sc3, sh3)
#undef FILM_COEF
    }

    float* p0 = &Aq[tid << 2];
    float* p1 = &d1[tid << 2];
    float* p2 = &d1[1024 + (tid << 2)];
    float* p3 = &d2[tid << 2];
    bool lowhalf = (tid < 128);
    float scA = lowhalf ? sc0 : sc3, shA = lowhalf ? sh0 : sh3;

    float4 f0 = *(float4*)p0, f1 = *(float4*)p1, f2v = *(float4*)p2, f3 = *(float4*)p3;
#define FILMV(V, SC, SH)                                                   \
    { V.x = fmaf(V.x, SC, SH); V.y = fmaf(V.y, SC, SH);                    \
      V.z = fmaf(V.z, SC, SH); V.w = fmaf(V.w, SC, SH); }
    FILMV(f0, scA, shA) FILMV(f1, sc1, sh1) FILMV(f2v, sc1, sh1) FILMV(f3, sc2, sh2)
#undef FILMV
    float sA = fabsf(f0.x) + fabsf(f0.y) + fabsf(f0.z) + fabsf(f0.w);
    float s1 = fabsf(f1.x) + fabsf(f1.y) + fabsf(f1.z) + fabsf(f1.w)
             + fabsf(f2v.x) + fabsf(f2v.y) + fabsf(f2v.z) + fabsf(f2v.w);
    float s2 = fabsf(f3.x) + fabsf(f3.y) + fabsf(f3.z) + fabsf(f3.w);
#pragma unroll
    for (int off = 32; off > 0; off >>= 1) {
        sA += __shfl_xor(sA, off);
        s1 += __shfl_xor(s1, off);
        s2 += __shfl_xor(s2, off);
    }
    if ((tid & 63) == 0)
        ((float4*)Bq)[tid >> 6] = make_float4(lowhalf ? sA : 0.f, s1, s2,
                                              lowhalf ? 0.f : sA);
    __syncthreads();
    float4 r0 = ((const float4*)Bq)[0];
    float4 r1 = ((const float4*)Bq)[1];
    float4 r2 = ((const float4*)Bq)[2];
    float4 r3 = ((const float4*)Bq)[3];
    float lam0 = log1pf(expf(lam_raw[0])) * ((r0.x + r1.x + r2.x + r3.x) * (1.0f / 512.f));
    float lam1 = log1pf(expf(lam_raw[1])) * ((r0.y + r1.y + r2.y + r3.y) * (1.0f / 2048.f));
    float lam2 = log1pf(expf(lam_raw[2])) * ((r0.z + r1.z + r2.z + r3.z) * (1.0f / 1024.f));
    float lam3 = log1pf(expf(lam_raw[3])) * ((r0.w + r1.w + r2.w + r3.w) * (1.0f / 512.f));
    if (tid < 4) {
        float lam = (tid == 0) ? lam0 : (tid == 1) ? lam1 : (tid == 2) ? lam2 : lam3;
        lam_ws[((size_t)(b * 4 + tid)) * 128 + h] = lam;
    }
    float lamA = lowhalf ? lam0 : lam3;
#define THRV(V, LAM)                                                       \
    { float a;                                                             \
      a = fabsf(V.x) - (LAM); V.x = (a > 0.f) ? copysignf(a, V.x) : 0.f;   \
      a = fabsf(V.y) - (LAM); V.y = (a > 0.f) ? copysignf(a, V.y) : 0.f;   \
      a = fabsf(V.z) - (LAM); V.z = (a > 0.f) ? copysignf(a, V.z) : 0.f;   \
      a = fabsf(V.w) - (LAM); V.w = (a > 0.f) ? copysignf(a, V.w) : 0.f; }
    THRV(f0, lamA) THRV(f1, lam1) THRV(f2v, lam1) THRV(f3, lam2)
#undef THRV
    *(float4*)p0 = f0; *(float4*)p1 = f1; *(float4*)p2 = f2v; *(float4*)p3 = f3;
    __syncthreads();

    synth_step(Aq, Aq + 512, Bq, 512, tid);      // R1 -> Bq[0:1024]
    __syncthreads();
    synth_step(Bq, d2, Aq, 1024, tid);           // R2 -> Aq[0:2048]
    __syncthreads();
    for (int q = tid; q < 512; q += 256) {       // R3 + residual + store
        int m0 = q << 2;
        int i0 = m0 << 1;
        float ov[8];
        synth_oct(Aq, d1, m0, 2048, ov);
        ushort8 zin = *(const ushort8*)(zg + i0);
        ushort8 o8;
#pragma unroll
        for (int t = 0; t < 8; ++t) o8[t] = f2b(ov[t] + b2f(zin[t]));
        *(ushort8*)(sg + i0) = o8;
    }
}

// ---------------- mix: u64-paired LDS transpose, operand-swapped MFMA -> D[g][l] ----------------

union U32x4S8 { unsigned int u[4]; short8 s; };

__global__ __launch_bounds__(256) void mix_kernel(const unsigned short* __restrict__ s_bf,
                                                  const unsigned short* __restrict__ Bmix,
                                                  const float* __restrict__ b_mix,
                                                  const float* __restrict__ mask,
                                                  float* __restrict__ out,
                                                  float* __restrict__ pool_part) {
    __shared__ unsigned int T[HD * 32];   // 16 KB: T2[h2][lp] u64 pairs {row 2h2, row 2h2+1}
    __shared__ float pbuf[2][HD];

    int blk = blockIdx.x;
    int b = blk >> 6;
    int lt64 = blk & 63;
    int l0 = lt64 << 6;
    int tid = threadIdx.x;
    int lane = tid & 63;
    int w = tid >> 6;
    int l_half = w >> 1, g_half = w & 1;
    int ln15 = lane & 15, lq4 = lane >> 4;

    {
        const unsigned int* src = (const unsigned int*)s_bf;
#pragma unroll
        for (int r = 0; r < 4; ++r) {
            int q = (r << 8) + tid;              // 0..1023
            int hh = q >> 3;                     // 0..127
            int k = q & 7;                       // 16B chunk
            uint4 v = *(const uint4*)(src + (size_t)(b * HD + hh) * (LL / 2) +
                                      (l0 >> 1) + (k << 2));
            int h2 = hh >> 1, par = hh & 1, sw = h2 & 31;
            unsigned int* tp = T + (h2 << 6);    // 64 u32 per h2 row
            tp[((((k << 2) + 0) ^ sw) << 1) + par] = v.x;
            tp[((((k << 2) + 1) ^ sw) << 1) + par] = v.y;
            tp[((((k << 2) + 2) ^ sw) << 1) + par] = v.z;
            tp[((((k << 2) + 3) ^ sw) << 1) + par] = v.w;
        }
    }
    __syncthreads();

    floatx4 acc[2][4];
#pragma unroll
    for (int i = 0; i < 2; ++i)
#pragma unroll
        for (int j = 0; j < 4; ++j) acc[i][j] = (floatx4){0.f, 0.f, 0.f, 0.f};

    const unsigned short* Bb = Bmix + (g_half * 64 + ln15) * 8;

#pragma unroll 2
    for (int ks = 0; ks < 4; ++ks) {
        int koct = ks * 4 + lq4;
        short8 a[2], bb[4];
#pragma unroll
        for (int lt = 0; lt < 2; ++lt) {
            int l_loc = l_half * 32 + lt * 16 + ln15;
            int lp = l_loc >> 1;
            int odd = l_loc & 1;
            U32x4S8 cv;
#pragma unroll
            for (int qq = 0; qq < 4; ++qq) {
                int h2 = (koct << 2) + qq;       // (koct*8 + 2qq)/2
                int sw = h2 & 31;
                uint2 w01 = *(const uint2*)&T[(h2 << 6) + ((lp ^ sw) << 1)];
                unsigned int e0 = odd ? (w01.x >> 16) : (w01.x & 0xffffu);
                unsigned int e1 = odd ? (w01.y >> 16) : (w01.y & 0xffffu);
                cv.u[qq] = e0 | (e1 << 16);
            }
            a[lt] = cv.s;
        }
#pragma unroll
        for (int gt = 0; gt < 4; ++gt)
            bb[gt] = *(const short8*)(Bb + (size_t)koct * 1024 + gt * 128);
        // swapped operands: D[g][l]
#pragma unroll
        for (int lt = 0; lt < 2; ++lt)
#pragma unroll
            for (int gt = 0; gt < 4; ++gt)
                acc[lt][gt] = __builtin_amdgcn_mfma_f32_16x16x32_bf16(bb[gt], a[lt], acc[lt][gt], 0, 0, 0);
    }

    // epilogue: lane = fixed l (ln15), regs = 4 consecutive g
    float4 pacc4[4];
#pragma unroll
    for (int gt = 0; gt < 4; ++gt) pacc4[gt] = make_float4(0.f, 0.f, 0.f, 0.f);

#pragma unroll
    for (int lt = 0; lt < 2; ++lt) {
        int l = l0 + l_half * 32 + lt * 16 + ln15;
        float mkv = mask[(size_t)b * LL + l];
        float* orow = out + ((size_t)b * LL + l) * HD;
#pragma unroll
        for (int gt = 0; gt < 4; ++gt) {
            int g0q = g_half * 64 + gt * 16 + (lq4 << 2);
            float4 bm = *(const float4*)&b_mix[g0q];
            float4 v;
            v.x = gelu_fast(acc[lt][gt][0] + bm.x) * mkv;
            v.y = gelu_fast(acc[lt][gt][1] + bm.y) * mkv;
            v.z = gelu_fast(acc[lt][gt][2] + bm.z) * mkv;
            v.w = gelu_fast(acc[lt][gt][3] + bm.w) * mkv;
            *(float4*)&orow[g0q] = v;
            pacc4[gt].x = fmaf(v.x, mkv, pacc4[gt].x);
            pacc4[gt].y = fmaf(v.y, mkv, pacc4[gt].y);
            pacc4[gt].z = fmaf(v.z, mkv, pacc4[gt].z);
            pacc4[gt].w = fmaf(v.w, mkv, pacc4[gt].w);
        }
    }
    // reduce over the 16 l-lanes (ln15 groups)
#pragma unroll
    for (int gt = 0; gt < 4; ++gt) {
#pragma unroll
        for (int off = 1; off <= 8; off <<= 1) {
            pacc4[gt].x += __shfl_xor(pacc4[gt].x, off);
            pacc4[gt].y += __shfl_xor(pacc4[gt].y, off);
            pacc4[gt].z += __shfl_xor(pacc4[gt].z, off);
            pacc4[gt].w += __shfl_xor(pacc4[gt].w, off);
        }
    }
    if (ln15 == 0) {
#pragma unroll
        for (int gt = 0; gt < 4; ++gt)
            *(float4*)&pbuf[l_half][g_half * 64 + gt * 16 + (lq4 << 2)] = pacc4[gt];
    }
    __syncthreads();
    if (tid < HD)
        pool_part[((size_t)(b * 64 + lt64)) * HD + tid] = pbuf[0][tid] + pbuf[1][tid];
}

// ---------------- finalize: denom + pool + lam mean/max ----------------

__global__ void finalize_kernel(const float* __restrict__ pool_part,
                                const float* __restrict__ mask,
                                const float* __restrict__ lam_ws,
                                float* __restrict__ d_out) {
    const size_t OUT1 = (size_t)BB * LL * HD;
    const size_t OUT2 = OUT1 + (size_t)BB * HD;
    const size_t OUT3 = OUT2 + BB;
    int b = blockIdx.x, tid = threadIdx.x;
    __shared__ float rsum[256], rmax[256];
    __shared__ float dsh;

    float ms = 0.f;
    const float4* mp = (const float4*)(mask + (size_t)b * LL);
    for (int i = tid; i < LL / 4; i += 256) {
        float4 m = mp[i];
        ms += m.x + m.y + m.z + m.w;
    }
    rsum[tid] = ms; __syncthreads();
    for (int st = 128; st > 0; st >>= 1) {
        if (tid < st) rsum[tid] += rsum[tid + st];
        __syncthreads();
    }
    if (tid == 0) dsh = fmaxf(rsum[0], 1.0f);
    __syncthreads();
    float denom = dsh;
    __syncthreads();

    // pool: 256 threads = 128 h x 2 halves (coalesced h-major reads, 32-deep chains)
    {
        int hh = tid & 127, half = tid >> 7;
        float s = 0.f;
        for (int blk = half * 32; blk < half * 32 + 32; ++blk)
            s += pool_part[((size_t)(b * 64 + blk)) * HD + hh];
        rsum[tid] = s;
        __syncthreads();
        if (tid < 128)
            d_out[OUT1 + (size_t)b * HD + tid] = (rsum[tid] + rsum[tid + 128]) / denom;
        __syncthreads();
    }

    float v0 = lam_ws[(size_t)b * 512 + tid];
    float v1 = lam_ws[(size_t)b * 512 + 256 + tid];
    rsum[tid] = v0 + v1;
    rmax[tid] = fmaxf(v0, v1);
    __syncthreads();
    for (int st = 128; st > 0; st >>= 1) {
        if (tid < st) {
            rsum[tid] += rsum[tid + st];
            rmax[tid] = fmaxf(rmax[tid], rmax[tid + st]);
        }
        __syncthreads();
    }
    if (tid == 0) {
        d_out[OUT2 + b] = rsum[0] / 512.0f;
        d_out[OUT3 + b] = rmax[0];
    }
}

// ---------------- launch ----------------

extern "C" void kernel_launch(void* const* d_in, const int* in_sizes, int n_in,
                              void* d_out, int out_size, void* d_ws, size_t ws_size,
                              hipStream_t stream) {
    (void)in_sizes; (void)n_in; (void)out_size; (void)ws_size;
    const float* x      = (const float*)d_in[0];
    const float* mask   = (const float*)d_in[1];
    const float* flow   = (const float*)d_in[2];
    const float* W_in   = (const float*)d_in[3];
    const float* b_in   = (const float*)d_in[4];
    const float* W_mix  = (const float*)d_in[5];
    const float* b_mix  = (const float*)d_in[6];
    const float* lam_raw= (const float*)d_in[7];
    const float* Wgb    = (const float*)d_in[8];
    const float* bgb    = (const float*)d_in[9];
    const float* Wg     = (const float*)d_in[10];
    const float* bg     = (const float*)d_in[11];

    unsigned short* z_bf = (unsigned short*)d_ws;                 // 8388608 ushort
    unsigned short* s_bf = z_bf + (size_t)BB * HD * LL;           // 8388608 ushort
    float* film_ws   = (float*)(s_bf + (size_t)BB * HD * LL);     // 16384
    float* gate_ws   = film_ws + BB * 4 * 256;                    // 64
    float* lam_ws    = gate_ws + 64;                              // 8192
    float* pool_part = lam_ws + BB * 4 * 128;                     // 16*64*128 = 131072
    unsigned short* Bmix = (unsigned short*)(pool_part + BB * 64 * HD);  // 16384 ushort

    float* out = (float*)d_out;

    hipLaunchKernelGGL(zproj_kernel, dim3(BB * 64 + 128), dim3(256), 0, stream,
                       x, mask, W_in, b_in, z_bf,
                       W_mix, Bmix, flow, Wgb, bgb, Wg, bg, film_ws, gate_ws);
    hipLaunchKernelGGL(wavelet_kernel, dim3(BB * HD), dim3(256), 0, stream,
                       z_bf, s_bf, film_ws, gate_ws, lam_raw, lam_ws);
    hipLaunchKernelGGL(mix_kernel, dim3(BB * (LL / 64)), dim3(256), 0, stream,
                       s_bf, Bmix, b_mix, mask, out, pool_part);
    hipLaunchKernelGGL(finalize_kernel, dim3(BB), dim3(256), 0, stream,
                       pool_part, mask, lam_ws, out);
}